// Round 4
// baseline (380.324 us; speedup 1.0000x reference)
//
#include <hip/hip_runtime.h>
#include <math.h>

#define NCH 32
#define CHV (64*32*64)      // one channel volume
#define NB 4
#define NT 64               // tiles per n: 8 z-tiles x 8 y-tiles
#define INVC (1.0f/(32.0f+1e-6f))
#define D2R 0.017453292519943295f
#define R2D 57.29577951308232f

// LDS slab geometry (pitch 68: +4 zeroed pad cols -> free x-edges, bank spread)
#define P0 68
#define F0REAL 4080         // 10z * 6y * 68
#define F0SZ 4096
#define F1REAL 3808         // 14z * 4y * 68
#define F1SZ 3840
#define F0B 4               // L[0..3] zero guard
#define F1B (4 + F0SZ)
#define BUFSZ (4 + F0SZ + F1SZ)   // 7940 floats per buffer

// ---------------------------------------------------------------------------
// Kernel 1: one block per (b, tile) computes ALL 3 rotations from one staged
// slab pair (the 14-row feat1 window covers every rotation). 12 waves:
// waves 0-3 -> rot 0 (-4deg), 4-7 -> rot 1 (0deg, identity), 8-11 -> rot 2.
// Double-buffered LDS, one barrier per channel, loads issued a phase early.
// ---------------------------------------------------------------------------
__global__ __launch_bounds__(768, 3) void k_heat(const float* __restrict__ feat0,
                                                 const float* __restrict__ feat1,
                                                 float* __restrict__ partial)
{
    __shared__ float L[2][BUFSZ];
    __shared__ float red[12][27];

    // XCD-chunked remap: round-robin dispatch -> contiguous same-b tile range/XCD
    const int lid = (int)blockIdx.y * 64 + (int)blockIdx.x;   // 0..255
    const int nid = (lid & 7) * 32 + (lid >> 3);
    const int b = nid >> 6;
    const int tile = nid & 63;
    const int zt = tile >> 3, yt = tile & 7;

    const int tid = (int)threadIdx.x;
    const int wv = tid >> 6;            // 0..11
    const int lane = tid & 63;
    const int rot = wv >> 2;            // 0,1,2
    const int ww = wv & 3;              // wave within rotation group
    const int tx = lane & 15, ty = lane >> 4;
    const int z0 = 8 * zt + 2 * ww;     // owns z0, z0+1
    const int x0 = 4 * tx;

    if (tid < 8) L[tid >> 2][tid & 3] = 0.0f;   // zero guards (both buffers)

    const float th = 4.0f * (float)(rot - 1) * D2R;
    const float cs = cosf(th), sn = sinf(th);

    // ---- bilinear setup (channel-invariant); rot==1 never uses it ----
    float WX0[2][4], WX1[2][4], WZ0[2][4], WZ1[2][4];
    int A1[2][4];
    #pragma unroll
    for (int j = 0; j < 2; ++j) {
        #pragma unroll
        for (int i = 0; i < 4; ++i) {
            const float rx = (float)(x0 + i) - 31.5f;
            const float rz = (float)(z0 + j) - 31.5f;
            const float sx = cs * rx - sn * rz + 31.5f;
            const float sz = sn * rx + cs * rz + 31.5f;
            const float xf = floorf(sx), zf = floorf(sz);
            const float fx = sx - xf, fz = sz - zf;
            const int ix = (int)xf, iz = (int)zf;
            WX0[j][i] = ((unsigned)ix < 64u) ? (1.0f - fx) : 0.0f;
            WX1[j][i] = ((unsigned)(ix + 1) < 64u) ? fx : 0.0f;
            WZ0[j][i] = 1.0f - fz;      // z-OOB rows staged as zeros
            WZ1[j][i] = fz;
            int zl = iz - (8 * zt - 3);
            zl = min(max(zl, 0), 12);
            const int bx = min(max(ix, -1), 63);
            A1[j][i] = F1B + (zl * 4 + ty) * P0 + bx;
        }
    }
    const int A1r1 = F1B + ((2 * ww + 3) * 4 + ty) * P0 + x0;   // identity rows

    // ---- staging map: 1984 float4 chunks, thread t takes f = t, t+768, t+1536 ----
    const float* f0b_ = feat0 + (size_t)b * NCH * CHV;
    const float* f1b_ = feat1 + (size_t)b * NCH * CHV;
    const float* gp[3];
    float gmask[3];
    int wof[3];
    const int nld = (tid < 448) ? 3 : 2;
    #pragma unroll
    for (int k = 0; k < 3; ++k) {
        const int f = tid + 768 * k;
        wof[k] = 4 + 4 * f;
        gmask[k] = 0.0f;
        gp[k] = f0b_;
        if (f < 1984) {
            if (f < 1024) {             // feat0 slab [10][6][68], zs/ys halo -1
                const int q = 4 * f;
                const int zr = q / 408; const int rem = q - zr * 408;
                const int yr = rem / 68; const int x = rem - yr * 68;
                const int zs = 8 * zt - 1 + zr, ys = 4 * yt - 1 + yr;
                const int ok = (q < F0REAL) & (x < 64) & (zs >= 0) & (zs < 64)
                             & (ys >= 0) & (ys < 32);
                gp[k] = f0b_ + (ok ? (zs * 2048 + ys * 64 + x) : 0);
                gmask[k] = ok ? 1.0f : 0.0f;
            } else {                    // feat1 slab [14][4][68], z halo -3
                const int q = 4 * f - 4096;
                const int zr = q / 272; const int rem = q - zr * 272;
                const int yr = rem / 68; const int x = rem - yr * 68;
                const int zs = 8 * zt - 3 + zr, ys = 4 * yt + yr;
                const int ok = (q < F1REAL) & (x < 64) & (zs >= 0) & (zs < 64);
                gp[k] = f1b_ + (ok ? (zs * 2048 + ys * 64 + x) : 0);
                gmask[k] = ok ? 1.0f : 0.0f;
            }
        }
    }

    const int rw = F0B + (2 * ww * 6 + ty) * P0 + x0;   // feat0 corr row base

    float acc[27];
    #pragma unroll
    for (int o = 0; o < 27; ++o) acc[o] = 0.0f;

    // ---- prologue: stage channel 0 into buffer 0 ----
    {
        float4 vv[3];
        #pragma unroll
        for (int k = 0; k < 3; ++k) if (k < nld) vv[k] = *(const float4*)gp[k];
        #pragma unroll
        for (int k = 0; k < 3; ++k) gp[k] += CHV;
        #pragma unroll
        for (int k = 0; k < 3; ++k) if (k < nld) {
            float4 v = vv[k]; const float m = gmask[k];
            v.x *= m; v.y *= m; v.z *= m; v.w *= m;
            *(float4*)&L[0][wof[k]] = v;
        }
    }
    __syncthreads();

    #pragma unroll 1
    for (int ch = 0; ch < NCH; ++ch) {
        const float* Lb = &L[ch & 1][0];

        // issue next channel's loads first (latency hides under compute)
        float4 nv[3];
        if (ch + 1 < NCH) {
            #pragma unroll
            for (int k = 0; k < 3; ++k) if (k < nld) nv[k] = *(const float4*)gp[k];
            #pragma unroll
            for (int k = 0; k < 3; ++k) gp[k] += CHV;
        }

        // ---- warp-sample 8 positions ----
        float fa[4], fb[4];
        if (rot == 1) {                 // identity rotation: direct rows
            const float4 a4 = *(const float4*)&Lb[A1r1];
            const float4 b4 = *(const float4*)&Lb[A1r1 + 4 * P0];
            fa[0] = a4.x; fa[1] = a4.y; fa[2] = a4.z; fa[3] = a4.w;
            fb[0] = b4.x; fb[1] = b4.y; fb[2] = b4.z; fb[3] = b4.w;
        } else {
            #pragma unroll
            for (int j = 0; j < 2; ++j) {
                #pragma unroll
                for (int i = 0; i < 4; ++i) {
                    const int a = A1[j][i];
                    const float p00 = Lb[a], p01 = Lb[a + 1];
                    const float p10 = Lb[a + 4 * P0], p11 = Lb[a + 4 * P0 + 1];
                    const float t = WZ0[j][i] * p00 + WZ1[j][i] * p10;
                    const float u = WZ0[j][i] * p01 + WZ1[j][i] * p11;
                    const float v_ = WX0[j][i] * t + WX1[j][i] * u;
                    if (j == 0) fa[i] = v_; else fb[i] = v_;
                }
            }
        }

        // ---- correlation: 12 feat0 rows serve both owned z, 27 offsets ----
        #pragma unroll
        for (int yri = 0; yri < 3; ++yri) {
            #pragma unroll
            for (int zri = 0; zri < 4; ++zri) {
                const int off = zri * 408 + yri * 68;
                const float4 m4 = *(const float4*)&Lb[rw + off];
                const float e0 = Lb[rw + off - 1];
                const float e1 = Lb[rw + off + 4];
                const int oy1 = 2 - yri;
                if (zri <= 2) {         // owned z0: oz+1 = 2-zri
                    const int ob = (2 - zri) * 9 + oy1 * 3;
                    acc[ob + 0] += fa[0] * m4.y + fa[1] * m4.z + fa[2] * m4.w + fa[3] * e1;
                    acc[ob + 1] += fa[0] * m4.x + fa[1] * m4.y + fa[2] * m4.z + fa[3] * m4.w;
                    acc[ob + 2] += fa[0] * e0   + fa[1] * m4.x + fa[2] * m4.y + fa[3] * m4.z;
                }
                if (zri >= 1) {         // owned z0+1: oz+1 = 3-zri
                    const int ob = (3 - zri) * 9 + oy1 * 3;
                    acc[ob + 0] += fb[0] * m4.y + fb[1] * m4.z + fb[2] * m4.w + fb[3] * e1;
                    acc[ob + 1] += fb[0] * m4.x + fb[1] * m4.y + fb[2] * m4.z + fb[3] * m4.w;
                    acc[ob + 2] += fb[0] * e0   + fb[1] * m4.x + fb[2] * m4.y + fb[3] * m4.z;
                }
            }
        }

        // ---- write next channel into the other buffer ----
        if (ch + 1 < NCH) {
            float* Ln = &L[(ch + 1) & 1][0];
            #pragma unroll
            for (int k = 0; k < 3; ++k) if (k < nld) {
                float4 v = nv[k]; const float m = gmask[k];
                v.x *= m; v.y *= m; v.z *= m; v.w *= m;
                *(float4*)&Ln[wof[k]] = v;
            }
        }
        __syncthreads();
    }

    // ---- reduction (fixed order -> deterministic) ----
    #pragma unroll 1
    for (int o = 0; o < 27; ++o) {
        float v = acc[o];
        #pragma unroll
        for (int d = 32; d >= 1; d >>= 1) v += __shfl_down(v, d, 64);
        if (lane == 0) red[wv][o] = v;
    }
    __syncthreads();
    if (tid < 81) {
        const int rr = tid / 27, o = tid - rr * 27;
        const float v = red[rr * 4 + 0][o] + red[rr * 4 + 1][o]
                      + red[rr * 4 + 2][o] + red[rr * 4 + 3][o];
        partial[((size_t)(b * 3 + rr) * NT + tile) * 27 + o] = v;
    }
}

// ---------------------------------------------------------------------------
// Kernel 2: reduce partials -> heat, per-batch MLP, loss + matrices + params.
// ---------------------------------------------------------------------------
__global__ __launch_bounds__(128) void k_mlp(const float* __restrict__ partial,
                                             const float* __restrict__ camg,
                                             const float* __restrict__ W1,
                                             const float* __restrict__ b1,
                                             const float* __restrict__ W2,
                                             const float* __restrict__ b2,
                                             const float* __restrict__ W3,
                                             const float* __restrict__ b3,
                                             float* __restrict__ out,
                                             float* __restrict__ params)
{
    __shared__ float heat[324];
    __shared__ float f[81];
    __shared__ float h1[128];
    __shared__ float h2[128];
    __shared__ float denom_s;
    __shared__ float res[NB][8];
    const int tid = (int)threadIdx.x;

    for (int p = tid; p < 324; p += 128) {
        const int n = p / 27, o = p % 27;
        const float* pp = partial + (size_t)n * NT * 27 + o;
        float s = 0.0f;
        for (int t = 0; t < NT; ++t) s += pp[t * 27];
        heat[p] = s * INVC;
    }
    __syncthreads();

    for (int b = 0; b < NB; ++b) {
        if (tid < 81) {
            float v = heat[b * 81 + tid];
            f[tid] = (v >= 0.0f) ? v : 0.1f * v;
        }
        __syncthreads();
        if (tid == 0) {
            float ss = 0.0f;
            for (int k = 0; k < 81; ++k) ss += f[k] * f[k];
            denom_s = 1e-6f + sqrtf(ss);
        }
        __syncthreads();
        if (tid < 81) f[tid] = f[tid] / denom_s;
        __syncthreads();
        {
            float a = b1[tid];
            const float* wr = W1 + tid * 81;
            for (int k = 0; k < 81; ++k) a += wr[k] * f[k];
            h1[tid] = (a >= 0.0f) ? a : 0.1f * a;
        }
        __syncthreads();
        {
            float a = b2[tid];
            const float* wr = W2 + tid * 128;
            for (int k = 0; k < 128; ++k) a += wr[k] * h1[k];
            h2[tid] = (a >= 0.0f) ? a : 0.1f * a;
        }
        __syncthreads();
        if (tid < 4) {
            float a = b3[tid];
            const float* wr = W3 + tid * 128;
            for (int k = 0; k < 128; ++k) a += wr[k] * h2[k];
            res[b][4 + tid] = a;
        }
        __syncthreads();
        if (tid == 0) {
            const float r_out = res[b][4], yv = res[b][5], xv = res[b][6], zv = res[b][7];
            const float t2 = r_out * D2R;
            const float c2 = cosf(t2), s2 = sinf(t2);
            float* m = out + 1 + b * 16;
            m[0] = c2;  m[1] = 0.0f; m[2] = s2;  m[3] = -xv;
            m[4] = 0.0f; m[5] = 1.0f; m[6] = 0.0f; m[7] = -yv;
            m[8] = -s2; m[9] = 0.0f; m[10] = c2; m[11] = -zv;
            m[12] = 0.0f; m[13] = 0.0f; m[14] = 0.0f; m[15] = 1.0f;
            params[b * 8 + 0] = c2;
            params[b * 8 + 1] = s2;
            params[b * 8 + 2] = c2 * xv - s2 * zv;
            params[b * 8 + 3] = yv;
            params[b * 8 + 4] = s2 * xv + c2 * zv;
            res[b][0] = -xv; res[b][1] = -yv; res[b][2] = -zv;
            res[b][3] = atan2f(s2, c2) * R2D;
        }
        __syncthreads();
    }

    if (tid == 0) {
        float tl2 = 0.0f, dl2 = 0.0f;
        for (int b = 0; b < NB; ++b) {
            const float* g = camg + b * 16;
            const float dx = res[b][0] - g[3];
            const float dy = res[b][1] - g[7];
            const float dz = res[b][2] - g[11];
            tl2 += dx * dx + dy * dy + dz * dz;
            const float dg = atan2f(g[2], g[10]) * R2D;
            const float dd = res[b][3] - dg;
            dl2 += dd * dd;
        }
        out[0] = tl2 * 0.25f + dl2 * 0.25f;
    }
}

// ---------------------------------------------------------------------------
// Kernel 3: warp feat1 by estimated transform -> feat1_warped (d_out + 65).
// ---------------------------------------------------------------------------
__global__ __launch_bounds__(256) void k_warp(const float* __restrict__ feat1,
                                              const float* __restrict__ params,
                                              float* __restrict__ outw)
{
    const int b = blockIdx.y;
    const int p = (int)blockIdx.x * 256 + (int)threadIdx.x;
    const int z = p >> 11;
    const int y = (p >> 6) & 31;
    const int x = p & 63;

    const float cs = params[b * 8 + 0], sn = params[b * 8 + 1];
    const float tpx = params[b * 8 + 2], tpy = params[b * 8 + 3], tpz = params[b * 8 + 4];

    const float rx = (float)x - 31.5f;
    const float ry = (float)y - 15.5f;
    const float rz = (float)z - 31.5f;
    const float sx = cs * rx - sn * rz + tpx + 31.5f;
    const float sy = ry + tpy + 15.5f;
    const float sz = sn * rx + cs * rz + tpz + 31.5f;

    const float xf = floorf(sx), yf = floorf(sy), zf = floorf(sz);
    const float fx = sx - xf, fy = sy - yf, fz = sz - zf;
    const int ix = (int)xf, iy = (int)yf, iz = (int)zf;

    const float wx[2] = {1.0f - fx, fx};
    const float wy[2] = {1.0f - fy, fy};
    const float wz[2] = {1.0f - fz, fz};
    const int xs[2] = {min(max(ix, 0), 63), min(max(ix + 1, 0), 63)};
    const int ys[2] = {min(max(iy, 0), 31), min(max(iy + 1, 0), 31)};
    const int zs[2] = {min(max(iz, 0), 63), min(max(iz + 1, 0), 63)};
    const bool vx[2] = {(unsigned)ix < 64u, (unsigned)(ix + 1) < 64u};
    const bool vy[2] = {(unsigned)iy < 32u, (unsigned)(iy + 1) < 32u};
    const bool vz[2] = {(unsigned)iz < 64u, (unsigned)(iz + 1) < 64u};

    int idx[8]; float w[8];
    int q = 0;
    #pragma unroll
    for (int dz = 0; dz < 2; ++dz)
        #pragma unroll
        for (int dy = 0; dy < 2; ++dy)
            #pragma unroll
            for (int dx = 0; dx < 2; ++dx) {
                idx[q] = zs[dz] * 2048 + ys[dy] * 64 + xs[dx];
                w[q] = (vx[dx] && vy[dy] && vz[dz]) ? wx[dx] * wy[dy] * wz[dz] : 0.0f;
                ++q;
            }

    const float* f1b = feat1 + (size_t)b * NCH * CHV;
    float* ob = outw + (size_t)b * NCH * CHV;
    #pragma unroll 1
    for (int c = 0; c < NCH; ++c) {
        const float* f1c = f1b + (size_t)c * CHV;
        float a = 0.0f;
        #pragma unroll
        for (int k = 0; k < 8; ++k) a += w[k] * f1c[idx[k]];
        ob[(size_t)c * CHV + p] = a;
    }
}

// ---------------------------------------------------------------------------
extern "C" void kernel_launch(void* const* d_in, const int* in_sizes, int n_in,
                              void* d_out, int out_size, void* d_ws, size_t ws_size,
                              hipStream_t stream)
{
    (void)in_sizes; (void)n_in; (void)out_size; (void)ws_size;
    const float* feat0 = (const float*)d_in[0];
    const float* feat1 = (const float*)d_in[1];
    const float* camg  = (const float*)d_in[2];
    const float* W1 = (const float*)d_in[3];
    const float* b1 = (const float*)d_in[4];
    const float* W2 = (const float*)d_in[5];
    const float* b2 = (const float*)d_in[6];
    const float* W3 = (const float*)d_in[7];
    const float* b3 = (const float*)d_in[8];
    float* out = (float*)d_out;

    float* partial = (float*)d_ws;                 // 12*64*27 floats ~ 83 KB
    float* params  = partial + 12 * NT * 27;       // 32 floats

    dim3 g1(64, 4);
    hipLaunchKernelGGL(k_heat, g1, dim3(768), 0, stream, feat0, feat1, partial);
    hipLaunchKernelGGL(k_mlp, dim3(1), dim3(128), 0, stream,
                       partial, camg, W1, b1, W2, b2, W3, b3, out, params);
    dim3 g3((64*32*64) / 256, NB);
    hipLaunchKernelGGL(k_warp, g3, dim3(256), 0, stream, feat1, params, out + 65);
}